// Round 5
// baseline (963.109 us; speedup 1.0000x reference)
//
#include <hip/hip_runtime.h>

#define NC 4
#define GATHER_BETA 3.0f
#define SCATTER_BETA 1e10f

typedef float f4 __attribute__((ext_vector_type(4)));

__device__ __forceinline__ f4 ntload(const float* p) {
    return __builtin_nontemporal_load(reinterpret_cast<const f4*>(p));
}
__device__ __forceinline__ void ntstore(float* p, f4 v) {
    __builtin_nontemporal_store(v, reinterpret_cast<f4*>(p));
}

// Per-batch weights: gather softmax (beta=3) and scatter one-hot (beta=1e10,
// computed exp-free: exact argmax one-hot with tie-splitting — bit-equal to
// the f32 reference softmax for these magnitudes).
__device__ __forceinline__ void make_weights(const float* __restrict__ logits,
                                             int b, float* g, float* m) {
    float l[NC];
#pragma unroll
    for (int c = 0; c < NC; ++c) l[c] = logits[b * NC + c];

    float mg = -1e30f;
#pragma unroll
    for (int c = 0; c < NC; ++c) { g[c] = l[c] * GATHER_BETA; mg = fmaxf(mg, g[c]); }
    float sg = 0.0f;
#pragma unroll
    for (int c = 0; c < NC; ++c) { g[c] = expf(g[c] - mg); sg += g[c]; }
    float inv_sg = 1.0f / sg;
#pragma unroll
    for (int c = 0; c < NC; ++c) g[c] *= inv_sg;

    float s[NC];
    float mm = -1e30f;
#pragma unroll
    for (int c = 0; c < NC; ++c) { s[c] = l[c] * SCATTER_BETA; mm = fmaxf(mm, s[c]); }
    float cnt = 0.0f;
#pragma unroll
    for (int c = 0; c < NC; ++c) { m[c] = (s[c] == mm) ? 1.0f : 0.0f; cnt += m[c]; }
    float inv_cnt = 1.0f / cnt;
#pragma unroll
    for (int c = 0; c < NC; ++c) m[c] *= inv_cnt;
}

// Each thread owns 64 B (4 consecutive float4s) of every stream: a wave
// covers 4 KB contiguous per stream -> 4x longer HBM bursts than 16 B/thread.
__global__ __launch_bounds__(256) void predlayer_fused(
    const float* __restrict__ states_h,
    const float* __restrict__ states_c,
    const float* __restrict__ new_h,
    const float* __restrict__ new_c,
    const float* __restrict__ logits,
    float* __restrict__ out,
    long long total,      // bs*h*w*oc
    long long span)       // h*w*oc
{
    const long long base = (((long long)blockIdx.x * blockDim.x) + threadIdx.x) * 16;
    if (base >= total) return;

    const int b = (int)(base / span);   // 16 consecutive floats share one batch
    float g[NC], m[NC];
    make_weights(logits, b, g, m);

    float* out_gh = out;
    float* out_gc = out + total;
    float* out_uh = out + 2 * total;
    float* out_uc = out + 6 * total;

    f4 nh[4], ncv[4];
#pragma unroll
    for (int v = 0; v < 4; ++v) {
        nh[v]  = ntload(new_h + base + v * 4);
        ncv[v] = ntload(new_c + base + v * 4);
    }

    f4 gh[4], gc[4];
#pragma unroll
    for (int v = 0; v < 4; ++v) { gh[v] = (f4){0.f,0.f,0.f,0.f}; gc[v] = (f4){0.f,0.f,0.f,0.f}; }

#pragma unroll
    for (int c = 0; c < NC; ++c) {
        const long long off = (long long)c * total + base;
        const float w1 = 1.0f - m[c];

        f4 sh[4], sc[4];
#pragma unroll
        for (int v = 0; v < 4; ++v) {
            sh[v] = ntload(states_h + off + v * 4);
            sc[v] = ntload(states_c + off + v * 4);
        }
#pragma unroll
        for (int v = 0; v < 4; ++v) {
            gh[v] += g[c] * sh[v];
            gc[v] += g[c] * sc[v];
            ntstore(out_uh + off + v * 4, sh[v] * w1 + nh[v]  * m[c]);
            ntstore(out_uc + off + v * 4, sc[v] * w1 + ncv[v] * m[c]);
        }
    }

#pragma unroll
    for (int v = 0; v < 4; ++v) {
        ntstore(out_gh + base + v * 4, gh[v]);
        ntstore(out_gc + base + v * 4, gc[v]);
    }
}

extern "C" void kernel_launch(void* const* d_in, const int* in_sizes, int n_in,
                              void* d_out, int out_size, void* d_ws, size_t ws_size,
                              hipStream_t stream) {
    const float* states_h = (const float*)d_in[0];
    const float* states_c = (const float*)d_in[1];
    const float* new_h    = (const float*)d_in[2];
    const float* new_c    = (const float*)d_in[3];
    const float* logits   = (const float*)d_in[4];
    float* out = (float*)d_out;

    const long long total = in_sizes[2];               // bs*h*w*oc
    const long long nc    = in_sizes[0] / total;       // 4
    const long long bs    = in_sizes[4] / nc;          // 16
    const long long span  = total / bs;                // h*w*oc

    const int block = 256;
    const long long nthreads = total / 16;             // 64 B per stream per thread
    const int grid = (int)((nthreads + block - 1) / block);

    predlayer_fused<<<grid, block, 0, stream>>>(
        states_h, states_c, new_h, new_c, logits, out, total, span);
}

// Round 6
// 206.738 us; speedup vs baseline: 4.6586x; 4.6586x over previous
//
#include <hip/hip_runtime.h>

#define NC 4
#define GATHER_BETA 3.0f
#define SCATTER_BETA 1e10f

typedef float f4 __attribute__((ext_vector_type(4)));

__device__ __forceinline__ f4 ntload(const float* p) {
    return __builtin_nontemporal_load(reinterpret_cast<const f4*>(p));
}
__device__ __forceinline__ void ntstore(float* p, f4 v) {
    __builtin_nontemporal_store(v, reinterpret_cast<f4*>(p));
}

// Per-batch weights: gather softmax (beta=3) and scatter one-hot (beta=1e10,
// computed exp-free: exact argmax one-hot with tie-splitting — bit-equal to
// the f32 reference softmax for these magnitudes).
__device__ __forceinline__ void make_weights(const float* __restrict__ logits,
                                             int b, float* g, float* m) {
    float l[NC];
#pragma unroll
    for (int c = 0; c < NC; ++c) l[c] = logits[b * NC + c];

    float mg = -1e30f;
#pragma unroll
    for (int c = 0; c < NC; ++c) { g[c] = l[c] * GATHER_BETA; mg = fmaxf(mg, g[c]); }
    float sg = 0.0f;
#pragma unroll
    for (int c = 0; c < NC; ++c) { g[c] = expf(g[c] - mg); sg += g[c]; }
    float inv_sg = 1.0f / sg;
#pragma unroll
    for (int c = 0; c < NC; ++c) g[c] *= inv_sg;

    float s[NC];
    float mm = -1e30f;
#pragma unroll
    for (int c = 0; c < NC; ++c) { s[c] = l[c] * SCATTER_BETA; mm = fmaxf(mm, s[c]); }
    float cnt = 0.0f;
#pragma unroll
    for (int c = 0; c < NC; ++c) { m[c] = (s[c] == mm) ? 1.0f : 0.0f; cnt += m[c]; }
    float inv_cnt = 1.0f / cnt;
#pragma unroll
    for (int c = 0; c < NC; ++c) m[c] *= inv_cnt;
}

__device__ __forceinline__ void process_chunk(
    const float* __restrict__ states_h, const float* __restrict__ states_c,
    const float* __restrict__ new_h,    const float* __restrict__ new_c,
    float* __restrict__ out, long long total, long long idx4,
    const float* g, const float* m)
{
    const f4 nh  = ntload(new_h + idx4);
    const f4 ncv = ntload(new_c + idx4);

    float* out_gh = out;
    float* out_gc = out + total;
    float* out_uh = out + 2 * total;
    float* out_uc = out + 6 * total;

    f4 gh = (f4){0.f, 0.f, 0.f, 0.f};
    f4 gc = (f4){0.f, 0.f, 0.f, 0.f};

#pragma unroll
    for (int c = 0; c < NC; ++c) {
        const long long off = (long long)c * total + idx4;
        const f4 sh = ntload(states_h + off);
        const f4 sc = ntload(states_c + off);

        gh += g[c] * sh;
        gc += g[c] * sc;

        const float w1 = 1.0f - m[c];
        ntstore(out_uh + off, sh * w1 + nh  * m[c]);
        ntstore(out_uc + off, sc * w1 + ncv * m[c]);
    }

    ntstore(out_gh + idx4, gh);
    ntstore(out_gc + idx4, gc);
}

// Block-contiguous chunking: each block owns a contiguous 4096-float (16 KB)
// span of every stream. Per instruction, lane i accesses base + i*16 B
// (fully coalesced 1 KB wave transactions); successive iterations walk
// consecutive 4-KB segments -> long sequential HBM bursts per stream.
__global__ __launch_bounds__(256) void predlayer_fused(
    const float* __restrict__ states_h,
    const float* __restrict__ states_c,
    const float* __restrict__ new_h,
    const float* __restrict__ new_c,
    const float* __restrict__ logits,
    float* __restrict__ out,
    long long total,      // bs*h*w*oc
    long long span)       // h*w*oc
{
    const long long seg = (long long)blockIdx.x * 4096;  // block's float offset
    const long long tbase = seg + (long long)threadIdx.x * 4;

    // span % 4096 == 0, so the whole block shares one batch index (wave-uniform)
    const int b = (int)(seg / span);
    float g[NC], m[NC];
    make_weights(logits, b, g, m);

#pragma unroll
    for (int k = 0; k < 4; ++k) {
        process_chunk(states_h, states_c, new_h, new_c, out, total,
                      tbase + (long long)k * 1024, g, m);
    }
}

extern "C" void kernel_launch(void* const* d_in, const int* in_sizes, int n_in,
                              void* d_out, int out_size, void* d_ws, size_t ws_size,
                              hipStream_t stream) {
    const float* states_h = (const float*)d_in[0];
    const float* states_c = (const float*)d_in[1];
    const float* new_h    = (const float*)d_in[2];
    const float* new_c    = (const float*)d_in[3];
    const float* logits   = (const float*)d_in[4];
    float* out = (float*)d_out;

    const long long total = in_sizes[2];               // bs*h*w*oc = 12,582,912
    const long long nc    = in_sizes[0] / total;       // 4
    const long long bs    = in_sizes[4] / nc;          // 16
    const long long span  = total / bs;                // h*w*oc = 786,432

    const int grid = (int)(total / 4096);              // 3072 blocks
    predlayer_fused<<<grid, 256, 0, stream>>>(
        states_h, states_c, new_h, new_c, logits, out, total, span);
}

// Round 7
// 192.271 us; speedup vs baseline: 5.0091x; 1.0752x over previous
//
#include <hip/hip_runtime.h>

#define NC 4
#define GATHER_BETA 3.0f
#define SCATTER_BETA 1e10f

typedef float f4 __attribute__((ext_vector_type(4)));

__device__ __forceinline__ f4 ntload(const float* p) {
    return __builtin_nontemporal_load(reinterpret_cast<const f4*>(p));
}
__device__ __forceinline__ void ntstore(float* p, f4 v) {
    __builtin_nontemporal_store(v, reinterpret_cast<f4*>(p));
}

// Per-batch weights: gather softmax (beta=3) and scatter one-hot (beta=1e10,
// computed exp-free: exact argmax one-hot with tie-splitting — bit-equal to
// the f32 reference softmax for these magnitudes).
__device__ __forceinline__ void make_weights(const float* __restrict__ logits,
                                             int b, float* g, float* m) {
    float l[NC];
#pragma unroll
    for (int c = 0; c < NC; ++c) l[c] = logits[b * NC + c];

    float mg = -1e30f;
#pragma unroll
    for (int c = 0; c < NC; ++c) { g[c] = l[c] * GATHER_BETA; mg = fmaxf(mg, g[c]); }
    float sg = 0.0f;
#pragma unroll
    for (int c = 0; c < NC; ++c) { g[c] = expf(g[c] - mg); sg += g[c]; }
    float inv_sg = 1.0f / sg;
#pragma unroll
    for (int c = 0; c < NC; ++c) g[c] *= inv_sg;

    float s[NC];
    float mm = -1e30f;
#pragma unroll
    for (int c = 0; c < NC; ++c) { s[c] = l[c] * SCATTER_BETA; mm = fmaxf(mm, s[c]); }
    float cnt = 0.0f;
#pragma unroll
    for (int c = 0; c < NC; ++c) { m[c] = (s[c] == mm) ? 1.0f : 0.0f; cnt += m[c]; }
    float inv_cnt = 1.0f / cnt;
#pragma unroll
    for (int c = 0; c < NC; ++c) m[c] *= inv_cnt;
}

__device__ __forceinline__ void process_chunk(
    const float* __restrict__ states_h, const float* __restrict__ states_c,
    const float* __restrict__ new_h,    const float* __restrict__ new_c,
    float* __restrict__ out, long long total, long long idx4,
    const float* g, const float* m)
{
    const f4 nh  = ntload(new_h + idx4);
    const f4 ncv = ntload(new_c + idx4);

    float* out_gh = out;
    float* out_gc = out + total;
    float* out_uh = out + 2 * total;
    float* out_uc = out + 6 * total;

    f4 gh = (f4){0.f, 0.f, 0.f, 0.f};
    f4 gc = (f4){0.f, 0.f, 0.f, 0.f};

#pragma unroll
    for (int c = 0; c < NC; ++c) {
        const long long off = (long long)c * total + idx4;
        const f4 sh = ntload(states_h + off);
        const f4 sc = ntload(states_c + off);

        gh += g[c] * sh;
        gc += g[c] * sc;

        const float w1 = 1.0f - m[c];
        ntstore(out_uh + off, sh * w1 + nh  * m[c]);
        ntstore(out_uc + off, sc * w1 + ncv * m[c]);
    }

    ntstore(out_gh + idx4, gh);
    ntstore(out_gc + idx4, gc);
}

__global__ __launch_bounds__(256) void predlayer_fused(
    const float* __restrict__ states_h,
    const float* __restrict__ states_c,
    const float* __restrict__ new_h,
    const float* __restrict__ new_c,
    const float* __restrict__ logits,
    float* __restrict__ out,
    long long total,      // bs*h*w*oc
    long long span,       // h*w*oc
    int db)               // batch delta per chunk = bs/4
{
    const long long quarter = total >> 2;  // bs divisible by 4
    long long idx4 = (((long long)blockIdx.x * blockDim.x) + threadIdx.x) * 4;
    if (idx4 >= quarter) return;

    const int b0 = (int)(idx4 / span);     // single i64 div; chunk k batch = b0 + k*db

#pragma unroll
    for (int k = 0; k < 4; ++k) {
        float g[NC], m[NC];
        make_weights(logits, b0 + k * db, g, m);
        process_chunk(states_h, states_c, new_h, new_c, out, total,
                      idx4 + (long long)k * quarter, g, m);
    }
}

extern "C" void kernel_launch(void* const* d_in, const int* in_sizes, int n_in,
                              void* d_out, int out_size, void* d_ws, size_t ws_size,
                              hipStream_t stream) {
    const float* states_h = (const float*)d_in[0];
    const float* states_c = (const float*)d_in[1];
    const float* new_h    = (const float*)d_in[2];
    const float* new_c    = (const float*)d_in[3];
    const float* logits   = (const float*)d_in[4];
    float* out = (float*)d_out;

    const long long total = in_sizes[2];               // bs*h*w*oc
    const long long nc    = in_sizes[0] / total;       // 4
    const long long bs    = in_sizes[4] / nc;          // 16
    const long long span  = total / bs;                // h*w*oc

    const int block = 256;
    const long long nthreads = total / 16;             // 4 float4 chunks per thread
    const int grid = (int)((nthreads + block - 1) / block);

    predlayer_fused<<<grid, block, 0, stream>>>(
        states_h, states_c, new_h, new_c, logits, out, total, span, (int)(bs / 4));
}